// Round 4
// baseline (154.879 us; speedup 1.0000x reference)
//
#include <hip/hip_runtime.h>
#include <math.h>

#define NPTS   100000
#define NRAYS  4096
#define KTOP   10
#define KMER   12
#define CAP    128
#define LCAP   12

// scan R4: 4 pts/lane (2 packed pairs), 1024 pts/block, 98 pblks x 64 rchunks.
// Rationale: VALUBusy pinned ~55% at 4 waves/SIMD across R0/R1/R3 with a
// near-floor instruction stream (~2700 VALU/wave) -> occupancy is the lever.
// Halving per-lane state (~50-60 VGPR) doubles resident waves.
#define PPAIR  2
#define SBLK   98
#define RCS    64                 // ray chunks for scan
#define RPBS   (NRAYS / RCS)      // 64 rays per scan block

// theta R4: TRAYS 8->4 (1024 blocks): was 512 blocks = 2 blocks/CU = 2
// waves/SIMD, latency-exposed (R3's theta pipelining moved total-scan by
// ~10us -> theta is big). Same per-ray sample set + reduction order ->
// theta bit-identical.
#define TPAIR  4
#define NPART  64
#define TRAYS  4                  // rays per theta block
#define TGRP   16                 // point groups per block

typedef float v2f __attribute__((ext_vector_type(2)));

static_assert(SBLK * 1024 >= NPTS, "scan covers all points");
static_assert(TGRP * 2048 <= NPTS, "theta sample within real points");

__device__ __forceinline__ float4 make_center(const float* __restrict__ ro,
                                              const float* __restrict__ rd,
                                              int ray, float w) {
    float ox = ro[3 * ray + 0], oy = ro[3 * ray + 1], oz = ro[3 * ray + 2];
    float dx = rd[3 * ray + 0], dy = rd[3 * ray + 1], dz = rd[3 * ray + 2];
    float cx, cy, cz;
    {
#pragma clang fp contract(off)
        cx = ox + dx * 3.0f;
        cy = oy + dy * 3.0f;
        cz = oz + dz * 3.0f;
    }
    return make_float4(cx, cy, cz, w);
}

__device__ __forceinline__ float sigm(float x) { return 1.0f / (1.0f + expf(-x)); }

__device__ __forceinline__ float rfl(float x) {
    return __int_as_float(__builtin_amdgcn_readfirstlane(__float_as_int(x)));
}

__device__ __forceinline__ v2f score2(v2f px, v2f py, v2f pz, v2f pw,
                                      v2f rx, v2f ry, v2f rz) {
    v2f t = __builtin_elementwise_fma(pz, rz, pw);      // z,y,x order: matches
    t = __builtin_elementwise_fma(py, ry, t);           // prior kernel bit-for-bit
    return __builtin_elementwise_fma(px, rx, t);
}

__device__ __forceinline__ unsigned long long mkkey(float sc, int id, bool v) {
    unsigned u = __float_as_uint(sc);
    u = (u & 0x80000000u) ? ~u : (u | 0x80000000u);    // order-preserving f32->u32
    unsigned long long k = ((unsigned long long)u << 32) | (unsigned)(~id);
    return v ? k : 0ull;                               // smaller id -> larger key
}

// ---------------------------------------------------------------------------
// theta: block = 4 rays, 256 threads, 1024 blocks (3-4/CU). Sample = 32768
// pts, identical point set per ray as before (ids depend only on wave/lane/g)
// -> theta bit-identical. Group loop software-pipelined (A/B register
// buffers). launch_bounds(256,3): ~170 VGPR cap, 3 waves/SIMD floor.
// Writes c4[ray]=(cx,cy,cz,theta); cnt=0.
// ---------------------------------------------------------------------------
__global__ __launch_bounds__(256, 3) void theta_kernel(const float* __restrict__ xyz,
                                                       const float* __restrict__ ro,
                                                       const float* __restrict__ rd,
                                                       float4* __restrict__ c4,
                                                       int* __restrict__ cnt) {
    __shared__ float4 rsh[TRAYS];
    __shared__ float  Msh[4][TRAYS][64];               // 4 KB, lane-stride 1
    const int tid = threadIdx.x, wave = tid >> 6, lane = tid & 63;
    const int rbase = blockIdx.x * TRAYS;

    if (tid < TRAYS) rsh[tid] = make_center(ro, rd, rbase + tid, 0.0f);
    __syncthreads();

    float4 rr[TRAYS];
#pragma unroll
    for (int r = 0; r < TRAYS; ++r) rr[r] = rsh[r];    // rays -> registers, once

    v2f M[TRAYS];
#pragma unroll
    for (int r = 0; r < TRAYS; ++r) M[r] = (v2f){-INFINITY, -INFINITY};

    v2f pxA[TPAIR], pyA[TPAIR], pzA[TPAIR], pwA[TPAIR];
    v2f pxB[TPAIR], pyB[TPAIR], pzB[TPAIR], pwB[TPAIR];

    auto loadg = [&](v2f* PX, v2f* PY, v2f* PZ, v2f* PW, int g) {
        const int id0 = g * 2048 + wave * 512 + lane;
#pragma unroll
        for (int u = 0; u < TPAIR; ++u) {
            int ia = id0 + (2 * u) * 64, ib = id0 + (2 * u + 1) * 64;
            float xa = xyz[3 * ia + 0], ya = xyz[3 * ia + 1], za = xyz[3 * ia + 2];
            float xb = xyz[3 * ib + 0], yb = xyz[3 * ib + 1], zb = xyz[3 * ib + 2];
            PX[u] = (v2f){xa, xb}; PY[u] = (v2f){ya, yb}; PZ[u] = (v2f){za, zb};
            PW[u] = (v2f){-0.5f * fmaf(xa, xa, fmaf(ya, ya, za * za)),
                          -0.5f * fmaf(xb, xb, fmaf(yb, yb, zb * zb))};
        }
    };
    auto computeg = [&](const v2f* PX, const v2f* PY, const v2f* PZ, const v2f* PW) {
#pragma unroll
        for (int r = 0; r < TRAYS; ++r) {
            const v2f rx = (v2f){rr[r].x, rr[r].x};
            const v2f ry = (v2f){rr[r].y, rr[r].y};
            const v2f rz = (v2f){rr[r].z, rr[r].z};
            v2f m = M[r];
#pragma unroll
            for (int u = 0; u < TPAIR; ++u)
                m = __builtin_elementwise_max(m, score2(PX[u], PY[u], PZ[u], PW[u], rx, ry, rz));
            M[r] = m;
        }
    };

    loadg(pxA, pyA, pzA, pwA, 0);                      // prime the pipeline
#pragma unroll 1
    for (int g = 0; g < TGRP; g += 2) {
        loadg(pxB, pyB, pzB, pwB, g + 1);              // prefetch under compute(A)
        computeg(pxA, pyA, pzA, pwA);
        if (g + 2 < TGRP) loadg(pxA, pyA, pzA, pwA, g + 2);
        computeg(pxB, pyB, pzB, pwB);
    }

#pragma unroll
    for (int r = 0; r < TRAYS; ++r)
        Msh[wave][r][lane] = fmaxf(M[r].x, M[r].y);    // lane-stride 1: no conflict
    __syncthreads();

    if (tid < TRAYS) {                                 // theta = 10th of 64 parts
        float vs[KTOP];
#pragma unroll
        for (int j = 0; j < KTOP; ++j) vs[j] = -INFINITY;
#pragma unroll 1
        for (int p = 0; p < NPART; ++p) {
            float v = fmaxf(fmaxf(Msh[0][tid][p], Msh[1][tid][p]),
                            fmaxf(Msh[2][tid][p], Msh[3][tid][p]));
#pragma unroll
            for (int t = KTOP - 1; t >= 1; --t) {
                bool up = v > vs[t - 1], here = v > vs[t];
                vs[t] = up ? vs[t - 1] : (here ? v : vs[t]);
            }
            vs[0] = fmaxf(vs[0], v);
        }
        float4 c = rsh[tid];                           // center already in LDS
        c.w = vs[KTOP - 1];
        c4[rbase + tid] = c;                           // (cx,cy,cz,theta)
        cnt[rbase + tid] = 0;
    }
}

// ---------------------------------------------------------------------------
// scan: 4 pts/lane as 2 packed pairs, 1024 pts/block. Rays arrive as SGPRs
// (uniform c4 loads, readfirstlane at load time, one-batch-ahead prefetch in
// SGPRs = zero VGPR cost). Per-lane state ~50 VGPR -> target 8 waves/SIMD
// (was 4 at VGPR~128: VALUBusy stuck 55%). Emit machinery/flush/CAP
// unchanged from the proven R14 body.
// ---------------------------------------------------------------------------
__global__ __launch_bounds__(256, 6) void scan_kernel(const float* __restrict__ xyz,
                                                      const float4* __restrict__ c4,
                                                      int* __restrict__ cnt,
                                                      float2* __restrict__ cand) {
    __shared__ int    lcnt[RPBS];
    __shared__ float2 lbuf[RPBS][LCAP];
    const int pblk = blockIdx.x, rchunk = blockIdx.y;
    const int tid = threadIdx.x, wave = tid >> 6, lane = tid & 63;
    const int rbase = rchunk * RPBS;

    if (tid < RPBS) lcnt[tid] = 0;

    const int id0 = pblk * 1024 + wave * 256 + lane;
    v2f px[PPAIR], py[PPAIR], pz[PPAIR], pw[PPAIR];
#pragma unroll
    for (int u = 0; u < PPAIR; ++u) {
        int ia = id0 + (2 * u) * 64, ib = id0 + (2 * u + 1) * 64;
        bool va = ia < NPTS, vb = ib < NPTS;
        int ca = va ? ia : 0, cb = vb ? ib : 0;
        float xa = xyz[3 * ca + 0], ya = xyz[3 * ca + 1], za = xyz[3 * ca + 2];
        float xb = xyz[3 * cb + 0], yb = xyz[3 * cb + 1], zb = xyz[3 * cb + 2];
        px[u] = (v2f){xa, xb}; py[u] = (v2f){ya, yb}; pz[u] = (v2f){za, zb};
        pw[u] = (v2f){va ? -0.5f * fmaf(xa, xa, fmaf(ya, ya, za * za)) : -INFINITY,
                      vb ? -0.5f * fmaf(xb, xb, fmaf(yb, yb, zb * zb)) : -INFINITY};
    }
    __syncthreads();

    auto emit = [&](int r, float sc, int id) {
        int slot = atomicAdd(&lcnt[r], 1);             // LDS atomic
        float2 e = make_float2(sc, __int_as_float(id));
        if (slot < LCAP) lbuf[r][slot] = e;
        else {                                         // rare overflow
            int gs = atomicAdd(&cnt[rbase + r], 1);
            if (gs < CAP) cand[((rbase + r) << 7) + gs] = e;
        }
    };

    auto do_ray = [&](int r, float cx, float cy, float cz, float th) {
        const v2f rx = (v2f){cx, cx}, ry = (v2f){cy, cy}, rz = (v2f){cz, cz};
        v2f t0 = score2(px[0], py[0], pz[0], pw[0], rx, ry, rz);
        v2f t1 = score2(px[1], py[1], pz[1], pw[1], rx, ry, rz);
        float hm = fmaxf(fmaxf(t0.x, t0.y), fmaxf(t1.x, t1.y));

        if (__ballot(hm >= th)) {                      // rare wave-level gate
            if (t0.x >= th) emit(r, t0.x, id0 + 0 * 64);
            if (t0.y >= th) emit(r, t0.y, id0 + 1 * 64);
            if (t1.x >= th) emit(r, t1.x, id0 + 2 * 64);
            if (t1.y >= th) emit(r, t1.y, id0 + 3 * 64);
        }
    };

    float qx[4], qy[4], qz[4], qw[4];                  // SGPR ray batch
    float nx[4], ny[4], nz[4], nw[4];
#pragma unroll
    for (int j = 0; j < 4; ++j) {
        float4 t = c4[rbase + j];                      // uniform address
        qx[j] = rfl(t.x); qy[j] = rfl(t.y); qz[j] = rfl(t.z); qw[j] = rfl(t.w);
    }
#pragma unroll 1
    for (int rb = 0; rb < RPBS; rb += 4) {
        const bool more = (rb + 4 < RPBS);
        if (more) {
#pragma unroll
            for (int j = 0; j < 4; ++j) {              // prefetch next batch (SGPR)
                float4 t = c4[rbase + rb + 4 + j];
                nx[j] = rfl(t.x); ny[j] = rfl(t.y); nz[j] = rfl(t.z); nw[j] = rfl(t.w);
            }
        }
#pragma unroll
        for (int j = 0; j < 4; ++j) do_ray(rb + j, qx[j], qy[j], qz[j], qw[j]);
        if (more) {
#pragma unroll
            for (int j = 0; j < 4; ++j) { qx[j] = nx[j]; qy[j] = ny[j]; qz[j] = nz[j]; qw[j] = nw[j]; }
        }
    }

    __syncthreads();
    if (tid < RPBS) {                                  // bulk flush: 1 atomic/ray
        int n = lcnt[tid];
        n = n < LCAP ? n : LCAP;
        if (n > 0) {
            const int rayid = rbase + tid;
            int base = atomicAdd(&cnt[rayid], n);
            for (int j = 0; j < n; ++j) {
                int slot = base + j;
                if (slot < CAP) cand[(rayid << 7) + slot] = lbuf[tid][j];
            }
        }
    }
}

// ---------------------------------------------------------------------------
// merge: wave per ray (proven R6 body). Coalesced candidate load, top-12 via
// 12 wave-argmax rounds on packed keys, parallel f64 re-rank, rgb.
// ---------------------------------------------------------------------------
__global__ __launch_bounds__(256) void merge_kernel(const float* __restrict__ ro,
                                                    const float* __restrict__ rd,
                                                    const int* __restrict__ cnt,
                                                    const float2* __restrict__ cand,
                                                    const float* __restrict__ xyz,
                                                    const float* __restrict__ fdc,
                                                    const float* __restrict__ opac,
                                                    float* __restrict__ out) {
    const int wave = threadIdx.x >> 6, lane = threadIdx.x & 63;
    const int ray = blockIdx.x * 4 + wave;

    int n = cnt[ray];
    n = n < CAP ? n : CAP;

    const float2* cl = cand + (ray << 7);
    float2 e0 = cl[lane];                              // coalesced 512B wave-load
    float2 e1 = cl[64 + lane];
    int id0 = __float_as_int(e0.y), id1 = __float_as_int(e1.y);

    unsigned long long k0 = mkkey(e0.x, id0, lane < n);
    unsigned long long k1 = mkkey(e1.x, id1, lane + 64 < n);

    int sel = -1;                                      // lane j holds j-th best id
    unsigned long long kl = k0 > k1 ? k0 : k1;
#pragma unroll
    for (int j = 0; j < KMER; ++j) {
        unsigned long long m = kl;
#pragma unroll
        for (int off = 1; off < 64; off <<= 1) {
            unsigned long long o = __shfl_xor(m, off);
            m = m > o ? m : o;
        }
        bool win = (kl == m) && (m != 0ull);
        int wid = (k0 >= k1) ? id0 : id1;
        unsigned long long wmask = __ballot(win);
        int wl = __ffsll(wmask) - 1;                   // unique winner (keys unique)
        int bid = __shfl(wid, wl & 63);
        if (m == 0ull) bid = -1;
        if (lane == j) sel = bid;
        if (win) {
            if (k0 >= k1) k0 = 0ull; else k1 = 0ull;
            kl = k0 > k1 ? k0 : k1;
        }
    }

    float ox = ro[3 * ray + 0], oy = ro[3 * ray + 1], oz = ro[3 * ray + 2];
    float dx = rd[3 * ray + 0], dy = rd[3 * ray + 1], dz = rd[3 * ray + 2];
    float cxf, cyf, czf;
    {
#pragma clang fp contract(off)
        cxf = ox + dx * 3.0f;
        cyf = oy + dy * 3.0f;
        czf = oz + dz * 3.0f;
    }
    double Cx = (double)cxf, Cy = (double)cyf, Cz = (double)czf;
    double cn = Cx * Cx + Cy * Cy + Cz * Cz;

    bool valid = (lane < KMER) && (sel >= 0);
    int pid = valid ? sel : 0;
    double X = (double)xyz[3 * pid + 0];
    double Y = (double)xyz[3 * pid + 1];
    double Z = (double)xyz[3 * pid + 2];
    double sq = valid ? (cn + (X * X + Y * Y + Z * Z) - 2.0 * (Cx * X + Cy * Y + Cz * Z))
                      : (double)INFINITY;
    int cid = valid ? sel : 0x7fffffff;

    int rank = 0;
#pragma unroll
    for (int k = 0; k < KMER; ++k) {                   // rank among the 12
        double sk = __shfl(sq, k);
        int    ik = __shfl(cid, k);
        if ((sk < sq) || (sk == sq && ik < cid)) ++rank;
    }

    bool take = valid && (rank < KTOP);
    float w = 0.0f, rr = 0.0f, gg = 0.0f, bb = 0.0f;
    if (take) {                                        // parallel gathers, 10 lanes
        float dd = sqrtf(fmaxf((float)sq, 0.0f));
        w  = expf(-0.1f * dd) * sigm(opac[pid]);
        rr = w * sigm(fdc[3 * pid + 0]);
        gg = w * sigm(fdc[3 * pid + 1]);
        bb = w * sigm(fdc[3 * pid + 2]);
    }
#pragma unroll
    for (int off = 1; off < 64; off <<= 1) {
        w  += __shfl_xor(w,  off);
        rr += __shfl_xor(rr, off);
        gg += __shfl_xor(gg, off);
        bb += __shfl_xor(bb, off);
    }
    if (lane == 0) {
        float inv = 1.0f / (w + 1e-8f);
        out[3 * ray + 0] = rr * inv;
        out[3 * ray + 1] = gg * inv;
        out[3 * ray + 2] = bb * inv;
    }
}

// ---------------------------------------------------------------------------
extern "C" void kernel_launch(void* const* d_in, const int* in_sizes, int n_in,
                              void* d_out, int out_size, void* d_ws, size_t ws_size,
                              hipStream_t stream) {
    const float* rays_o = (const float*)d_in[0];
    const float* rays_d = (const float*)d_in[1];
    const float* xyz    = (const float*)d_in[2];
    const float* fdc    = (const float*)d_in[3];
    const float* opac   = (const float*)d_in[4];
    float* out = (float*)d_out;

    // ws: c4 64KB | cnt 16KB | cand 4.0MB
    char* w = (char*)d_ws;
    float4* c4   = (float4*)w;   w += (size_t)NRAYS * 16;
    int*    cnt  = (int*)w;      w += (size_t)NRAYS * 4;
    float2* cand = (float2*)w;

    theta_kernel<<<NRAYS / TRAYS, 256, 0, stream>>>(xyz, rays_o, rays_d, c4, cnt);
    scan_kernel<<<dim3(SBLK, RCS), 256, 0, stream>>>(xyz, c4, cnt, cand);
    merge_kernel<<<NRAYS / 4, 256, 0, stream>>>(rays_o, rays_d, cnt, cand, xyz, fdc, opac, out);
}